// Round 1
// 1195.919 us; speedup vs baseline: 1.0611x; 1.0611x over previous
//
#include <hip/hip_runtime.h>
#include <cstddef>

#define B_  8
#define C_  512
#define D_  16
#define H_  58
#define W_  58
#define C2_ 256
#define N_  196     // 4*7*7 pooled positions
#define SS  3366    // LDS d-slice stride (58*58=3364 +2; 3366%32=6 -> spreads d across banks)

// ---------------------------------------------------------------------------
// Kernel 1: depthwise conv(1,3,3) + bias + BN + ReLU + adaptive max pool
// one block per (b, c, do); input slab is contiguous and read exactly once.
// 512 threads: thread = (d: t&3, half: (t>>2)&1, pool: t>>3).
// Each thread computes 4 of the 8 conv-output rows of its 8x8 pool window
// (6 input rows), so per-thread LDS reads and VALU are halved vs the 256-thread
// version, and occupancy is 24 waves/CU (vs 12).
// ---------------------------------------------------------------------------
__global__ __launch_bounds__(512) void k_conv_pool(
    const float* __restrict__ x,  const float* __restrict__ w9,
    const float* __restrict__ bias, const float* __restrict__ gamma,
    const float* __restrict__ beta, const float* __restrict__ rmean,
    const float* __restrict__ rvar, float* __restrict__ ypool)
{
    __shared__ float lds[4 * SS];
    const int gid = blockIdx.x;
    const int dq = gid & 3;            // do (pool depth index)
    const int c  = (gid >> 2) & 511;
    const int b  = gid >> 11;
    const float* src = x + (((size_t)(b * C_ + c)) * D_ + (size_t)dq * 4) * (H_ * W_);

    const int t = threadIdx.x;
    // stage 4 contiguous d-slices (3364 floats each) into LDS, float4 loads
    for (int i = t; i < 3364; i += 512) {
        float4 v = ((const float4*)src)[i];
        int s = i / 841;               // 841 float4 per slice
        int r = i - s * 841;
        float* dst = lds + s * SS + r * 4;
        dst[0] = v.x; dst[1] = v.y; dst[2] = v.z; dst[3] = v.w;
    }

    // fold BN into conv: out = relu(conv*sc + shift)
    const float sc = gamma[c] * rsqrtf(rvar[c] + 1e-5f);
    const float sh = (bias[c] - rmean[c]) * sc + beta[c];
    float wk[9];
#pragma unroll
    for (int i = 0; i < 9; ++i) wk[i] = w9[c * 9 + i] * sc;

    __syncthreads();

    float acc = 0.0f;                  // relu output >= 0, so 0 is a safe identity
    const int d    = t & 3;
    const int half = (t >> 2) & 1;
    const int pool = t >> 3;
    if (pool < 49) {
        const int ho = pool / 7, wo = pool - ho * 7;
        // this thread's 4 output rows start at conv-out row 8*ho + 4*half,
        // needing input rows (8*ho + 4*half) .. (+5)
        const float* base = lds + d * SS + (8 * ho + 4 * half) * W_ + 8 * wo;
        float c1[8], c2[8];
#pragma unroll
        for (int r = 0; r < 6; ++r) {
            float v[10];
            // 5x float2 loads (8B aligned: all base/stride terms are even)
#pragma unroll
            for (int j = 0; j < 5; ++j) {
                float2 p = *(const float2*)(base + r * W_ + 2 * j);
                v[2 * j] = p.x; v[2 * j + 1] = p.y;
            }
            if (r >= 2) {              // complete conv-out local row r-2, relu, max
#pragma unroll
                for (int w = 0; w < 8; ++w) {
                    float val = c2[w] + wk[6]*v[w] + wk[7]*v[w+1] + wk[8]*v[w+2] + sh;
                    acc = fmaxf(acc, fmaxf(val, 0.0f));
                }
            }
            if (r >= 1 && r <= 4) {    // add middle-row partial for local row r-1
#pragma unroll
                for (int w = 0; w < 8; ++w)
                    c2[w] = c1[w] + wk[3]*v[w] + wk[4]*v[w+1] + wk[5]*v[w+2];
            }
            if (r <= 3) {              // top-row partial for local row r
#pragma unroll
                for (int w = 0; w < 8; ++w)
                    c1[w] = wk[0]*v[w] + wk[1]*v[w+1] + wk[2]*v[w+2];
            }
        }
    }
    // max over (d, half): bits 0,1 = d; bit 2 = half — all within one wave
    acc = fmaxf(acc, __shfl_xor(acc, 1));
    acc = fmaxf(acc, __shfl_xor(acc, 2));
    acc = fmaxf(acc, __shfl_xor(acc, 4));
    if (pool < 49 && (t & 7) == 0)
        ypool[((size_t)(b * C_ + c) * 4 + dq) * 49 + pool] = acc;
}

// ---------------------------------------------------------------------------
// Kernel 2: grouped 1x1 convs g/f/h: out[b,gc,n] = w[gc,0]*y[b,2gc,n] + w[gc,1]*y[b,2gc+1,n]
// ---------------------------------------------------------------------------
__global__ __launch_bounds__(256) void k_gfh(
    const float* __restrict__ y,
    const float* __restrict__ wg, const float* __restrict__ wf,
    const float* __restrict__ wh,
    float* __restrict__ g, float* __restrict__ f, float* __restrict__ h)
{
    int idx = blockIdx.x * 256 + threadIdx.x;     // b*C2*N + gc*N + n
    if (idx >= B_ * C2_ * N_) return;
    int n  = idx % N_;
    int gc = (idx / N_) % C2_;
    int b  = idx / (N_ * C2_);
    size_t yi = ((size_t)(b * C_ + 2 * gc)) * N_ + n;
    float y0 = y[yi], y1 = y[yi + N_];
    g[idx] = wg[2*gc] * y0 + wg[2*gc+1] * y1;
    f[idx] = wf[2*gc] * y0 + wf[2*gc+1] * y1;
    h[idx] = wh[2*gc] * y0 + wh[2*gc+1] * y1;
}

// ---------------------------------------------------------------------------
// Kernel 3a: S[b,i,j] = sum_c gflat[b, i*256+c] * f[b,c,j]; row softmax -> soft
// one block per (b,i). gmat row i is a CONTIGUOUS 256-float chunk (reshape trick).
// ---------------------------------------------------------------------------
__global__ __launch_bounds__(256) void k_att_soft(
    const float* __restrict__ g, const float* __restrict__ f,
    float* __restrict__ soft)
{
    const int b = blockIdx.x / N_;
    const int i = blockIdx.x % N_;
    __shared__ float gm[C2_];
    __shared__ float red[256];
    const int t = threadIdx.x;
    gm[t] = g[(size_t)b * C2_ * N_ + (size_t)i * C2_ + t];
    __syncthreads();

    float s = 0.f;
    if (t < N_) {
        const float* fb = f + (size_t)b * C2_ * N_;
#pragma unroll 4
        for (int c = 0; c < C2_; ++c)
            s += gm[c] * fb[c * N_ + t];
    }
    // block softmax over j = t in [0,196)
    red[t] = (t < N_) ? s : -3.4e38f;
    __syncthreads();
    for (int off = 128; off > 0; off >>= 1) {
        if (t < off) red[t] = fmaxf(red[t], red[t + off]);
        __syncthreads();
    }
    float mx = red[0];
    __syncthreads();
    float e = (t < N_) ? __expf(s - mx) : 0.f;
    red[t] = e;
    __syncthreads();
    for (int off = 128; off > 0; off >>= 1) {
        if (t < off) red[t] += red[t + off];
        __syncthreads();
    }
    float inv = 1.f / red[0];
    if (t < N_)
        soft[((size_t)b * N_ + i) * N_ + t] = e * inv;
}

// ---------------------------------------------------------------------------
// Kernel 3b: out[b,c,n] = sum_j h[b,c,j] * soft[b,j,n]; one block per (b,c)
// ---------------------------------------------------------------------------
__global__ __launch_bounds__(256) void k_att_out(
    const float* __restrict__ h, const float* __restrict__ soft,
    float* __restrict__ out)
{
    const int b = blockIdx.x / C2_;
    const int c = blockIdx.x % C2_;
    __shared__ float hr[N_];
    const int t = threadIdx.x;
    if (t < N_) hr[t] = h[((size_t)b * C2_ + c) * N_ + t];
    __syncthreads();
    if (t >= N_) return;
    const float* sb = soft + (size_t)b * N_ * N_;
    float acc = 0.f;
#pragma unroll 4
    for (int j = 0; j < N_; ++j)
        acc += hr[j] * sb[j * N_ + t];
    out[((size_t)b * C2_ + c) * N_ + t] = acc;
}

// ---------------------------------------------------------------------------
extern "C" void kernel_launch(void* const* d_in, const int* in_sizes, int n_in,
                              void* d_out, int out_size, void* d_ws, size_t ws_size,
                              hipStream_t stream)
{
    const float* x      = (const float*)d_in[0];
    const float* conv1w = (const float*)d_in[1];   // (C,1,1,3,3) = C x 9
    const float* conv1b = (const float*)d_in[2];
    const float* gamma  = (const float*)d_in[3];
    const float* beta   = (const float*)d_in[4];
    const float* rmean  = (const float*)d_in[5];
    const float* rvar   = (const float*)d_in[6];
    const float* wg     = (const float*)d_in[7];   // (C2, 2)
    const float* wf     = (const float*)d_in[8];
    const float* wh     = (const float*)d_in[9];
    float* out = (float*)d_out;

    // workspace layout (floats)
    float* ws    = (float*)d_ws;
    float* ypool = ws;                                  // B*C*196   = 802816
    float* g     = ypool + (size_t)B_ * C_ * N_;        // B*C2*196  = 401408
    float* f     = g + (size_t)B_ * C2_ * N_;
    float* h     = f + (size_t)B_ * C2_ * N_;
    float* soft  = h + (size_t)B_ * C2_ * N_;           // B*196*196 = 307328

    k_conv_pool<<<B_ * C_ * 4, 512, 0, stream>>>(x, conv1w, conv1b, gamma, beta,
                                                 rmean, rvar, ypool);
    k_gfh<<<(B_ * C2_ * N_) / 256, 256, 0, stream>>>(ypool, wg, wf, wh, g, f, h);
    k_att_soft<<<B_ * N_, 256, 0, stream>>>(g, f, soft);
    k_att_out<<<B_ * C2_, 256, 0, stream>>>(h, soft, out);
}